// Round 8
// baseline (95.420 us; speedup 1.0000x reference)
//
#include <hip/hip_runtime.h>

// NonLocalMean: x (4,64,128,128) fp32, K=7 (rad 3), HEADS=4 -> mid=16.
// w_p = exp(2<n_p,c> - ||n_p||^2 - ||c||^2) = exp(-||n_p-c||^2) <= 1 (softmax
// max is 0 at the center) -> plain sum. out = x + (sum w_p n_p)/(sum w_p).
// Zero-padded OOB patches are zero vectors contributing exp(-||c||^2).
//
// R8: occupancy is the binding constraint (every ~30us round ran ~2 waves/
// SIMD; the only >60% VALUBusy round ran 16 waves/CU). Fix: thread =
// (pixel, channel-HALF). 8 channels/thread -> ~50 VGPR -> 8 waves/SIMD.
// The 16-ch dot is completed by a full-rate DPP quad_perm(1,0,3,2) lane-
// pair exchange (+add) per visit -- VALU pipe, no LDS. 512-thread blocks
// (256 px x 2 halves), grid 1024 = 4 blocks/CU = 32 waves/CU, zero tail.
// Record: 40B = 8 packed-bf16 dwords + fp32 norm (quantized) at d8; half h
// reads 2 x ds_read_b64 at d{4h..4h+3} + broadcast b32 norm. Center exact
// fp32 from global (residual + dot accuracy; -||n_q - c||^2 stays exact).
// Both window loops rolled: live set structurally bounded, no hoist-spill.

#define TW    16
#define RAD   3
#define HWD   22                 // 16 + 6
#define NPIX  (HWD * HWD)        // 484
#define MID   16
#define PSTRD 10                 // dwords per record (40 B)
#define IMG   128
#define PLANE (IMG * IMG)

__device__ __forceinline__ unsigned bf16rne(float v) {
    unsigned u = __float_as_uint(v);
    u += 0x7fffu + ((u >> 16) & 1u);
    return u >> 16;
}
__device__ __forceinline__ float bl(unsigned u) { return __uint_as_float(u << 16); }
__device__ __forceinline__ float bh(unsigned u) { return __uint_as_float(u & 0xffff0000u); }

// lane-pair (xor 1) exchange + add via full-rate DPP quad_perm(1,0,3,2)
__device__ __forceinline__ float xor1_sum(float v) {
    int o = __builtin_amdgcn_update_dpp(0, __float_as_int(v),
                                        0xB1 /*quad_perm 1,0,3,2*/,
                                        0xF, 0xF, true);
    return v + __int_as_float(o);
}

__global__ __launch_bounds__(512, 8)
void nlm_kernel(const float* __restrict__ x, float* __restrict__ out) {
    const int g   = blockIdx.z & 3;
    const int b   = blockIdx.z >> 2;
    const int tx0 = blockIdx.x * TW;
    const int ty0 = blockIdx.y * TW;

    __shared__ __align__(8) unsigned recd[NPIX * PSTRD];   // 19,360 B

    const int tid  = threadIdx.x;        // 0..511
    const int half = tid & 1;            // channel half
    const int pix  = tid >> 1;           // 0..255
    const int lx   = pix & 15;
    const int ly   = pix >> 4;
    const float* xb = x + (size_t)(b * 64 + g * MID) * PLANE;

    // ---- stage halo: bf16-packed channels + fp32 norm (of quantized) ----
    if (tid < NPIX) {
        const int yy = tid / HWD;
        const int xx = tid - yy * HWD;
        const int gy = ty0 + yy - RAD;
        const int gx = tx0 + xx - RAD;
        const bool in = ((unsigned)gy < (unsigned)IMG) & ((unsigned)gx < (unsigned)IMG);
        const float* p = xb + gy * IMG + gx;
        unsigned pk[8];
        float ss = 0.f;
        #pragma unroll
        for (int k = 0; k < 8; ++k) {
            const float v0 = in ? p[(2 * k) * PLANE] : 0.f;
            const float v1 = in ? p[(2 * k + 1) * PLANE] : 0.f;
            const unsigned q0 = bf16rne(v0);
            const unsigned q1 = bf16rne(v1);
            pk[k] = q0 | (q1 << 16);
            const float r0 = bl(q0 << 16 ? q0 << 16 : 0u);  // quantized values
            const float r1 = __uint_as_float(q1 << 16);
            const float r0f = __uint_as_float(q0 << 16);
            ss = fmaf(r0f, r0f, ss);
            ss = fmaf(r1, r1, ss);
            (void)r0;
        }
        unsigned* rp = &recd[tid * PSTRD];
        #pragma unroll
        for (int k = 0; k < 4; ++k)
            *reinterpret_cast<uint2*>(rp + 2 * k) = make_uint2(pk[2 * k], pk[2 * k + 1]);
        rp[8] = __float_as_uint(ss);
    }
    __syncthreads();

    // ---- exact fp32 center, own 8 channels; cc completed via DPP ----
    const float* cp = xb + (size_t)(half * 8) * PLANE + (ty0 + ly) * IMG + (tx0 + lx);
    float ctr[8];
    #pragma unroll
    for (int c = 0; c < 8; ++c) ctr[c] = cp[c * PLANE];
    float cch = 0.f;
    #pragma unroll
    for (int c = 0; c < 8; ++c) cch = fmaf(ctr[c], ctr[c], cch);
    const float cc = xor1_sum(cch);

    float acc[8];
    #pragma unroll
    for (int c = 0; c < 8; ++c) acc[c] = 0.f;
    float s = 0.f;

    // ---- 49 visits; both loops rolled (bounded live set) ----
    #pragma unroll 1
    for (int wy = 0; wy < 7; ++wy) {
        const unsigned* rp = &recd[((ly + wy) * HWD + lx) * PSTRD + 4 * half];
        #pragma unroll 2
        for (int wx = 0; wx < 7; ++wx) {
            const uint2 q0 = *reinterpret_cast<const uint2*>(rp + 0);
            const uint2 q1 = *reinterpret_cast<const uint2*>(rp + 2);
            const float nn = __uint_as_float(rp[8 - 4 * half]);  // d8 broadcast
            float nb[8];
            nb[0] = bl(q0.x); nb[1] = bh(q0.x);
            nb[2] = bl(q0.y); nb[3] = bh(q0.y);
            nb[4] = bl(q1.x); nb[5] = bh(q1.x);
            nb[6] = bl(q1.y); nb[7] = bh(q1.y);
            float d0 = 0.f, d1 = 0.f;
            #pragma unroll
            for (int c = 0; c < 8; c += 2) {
                d0 = fmaf(nb[c + 0], ctr[c + 0], d0);
                d1 = fmaf(nb[c + 1], ctr[c + 1], d1);
            }
            const float dot = xor1_sum(d0 + d1);        // full 16-ch dot
            const float w = __expf(fmaf(2.f, dot, -(nn + cc)));
            s += w;
            #pragma unroll
            for (int c = 0; c < 8; ++c) acc[c] = fmaf(w, nb[c], acc[c]);
            rp += PSTRD;
        }
    }

    const float inv = 1.f / s;
    float* ob = out + (size_t)(b * 64 + g * MID + half * 8) * PLANE
                    + (size_t)(ty0 + ly) * IMG + (tx0 + lx);
    #pragma unroll
    for (int c = 0; c < 8; ++c)
        ob[c * PLANE] = fmaf(acc[c], inv, ctr[c]);
}

extern "C" void kernel_launch(void* const* d_in, const int* in_sizes, int n_in,
                              void* d_out, int out_size, void* d_ws, size_t ws_size,
                              hipStream_t stream) {
    const float* x = (const float*)d_in[0];
    float* out = (float*)d_out;
    dim3 grid(IMG / TW, IMG / TW, 16);   // 8 x 8 x (B=4 * HEADS=4) = 1024 blocks
    nlm_kernel<<<grid, 512, 0, stream>>>(x, out);
}

// Round 9
// 32.597 us; speedup vs baseline: 2.9272x; 2.9272x over previous
//
#include <hip/hip_runtime.h>

// NonLocalMean: x (4,64,128,128) fp32, K=7 (rad 3), HEADS=4 -> mid=16.
// w_p = exp(2<n_p,c> - ||n_p||^2 - ||c||^2) = exp(-||n_p-c||^2) <= 1 (softmax
// max is 0 at the center) -> plain sum. out = x + (sum w_p n_p)/(sum w_p).
// Zero-padded OOB patches are zero vectors contributing exp(-||c||^2).
//
// R9 = R8 structure (thread = pixel x channel-HALF, 8 ch/thread, DPP
// quad_perm lane-pair exchange completes the 16-ch dot) but UNCAPPED.
// Lesson from R4/R6/R8: launch_bounds min-occupancy args force spill
// disasters (WRITE_SIZE 230-330MB); lesson from R3/R5/R7: uncapped dense
// 16-ch bodies land >128 VGPR -> 2 waves/SIMD -> 30us latency plateau.
// This body's natural state is ~half (ctr[8]+acc[8]+one visit in flight),
// so uncapped it should land ~50-75 VGPR -> 6-8 waves/SIMD. wx loop kept
// at unroll 1 so only one visit's loads are ever live.
// Record: 40B = 8 packed-bf16 dwords + fp32 norm (of quantized values, so
// exp<=1 stays exact) at dword 8. Half h reads 2 x ds_read_b64 + b32 norm.
// Center exact fp32 from global (residual accuracy). One barrier total.

#define TW    16
#define RAD   3
#define HWD   22                 // 16 + 6
#define NPIX  (HWD * HWD)        // 484
#define MID   16
#define PSTRD 10                 // dwords per record (40 B)
#define IMG   128
#define PLANE (IMG * IMG)

__device__ __forceinline__ unsigned bf16rne(float v) {
    unsigned u = __float_as_uint(v);
    u += 0x7fffu + ((u >> 16) & 1u);
    return u >> 16;
}
__device__ __forceinline__ float bl(unsigned u) { return __uint_as_float(u << 16); }
__device__ __forceinline__ float bh(unsigned u) { return __uint_as_float(u & 0xffff0000u); }

// lane-pair (xor 1) exchange + add via full-rate DPP quad_perm(1,0,3,2)
__device__ __forceinline__ float xor1_sum(float v) {
    int o = __builtin_amdgcn_update_dpp(0, __float_as_int(v),
                                        0xB1 /*quad_perm 1,0,3,2*/,
                                        0xF, 0xF, true);
    return v + __int_as_float(o);
}

__global__ __launch_bounds__(512)
void nlm_kernel(const float* __restrict__ x, float* __restrict__ out) {
    const int g   = blockIdx.z & 3;
    const int b   = blockIdx.z >> 2;
    const int tx0 = blockIdx.x * TW;
    const int ty0 = blockIdx.y * TW;

    __shared__ __align__(8) unsigned recd[NPIX * PSTRD];   // 19,360 B

    const int tid  = threadIdx.x;        // 0..511
    const int half = tid & 1;            // channel half
    const int pix  = tid >> 1;           // 0..255
    const int lx   = pix & 15;
    const int ly   = pix >> 4;
    const float* xb = x + (size_t)(b * 64 + g * MID) * PLANE;

    // ---- stage halo: bf16-packed channels + fp32 norm (of quantized) ----
    if (tid < NPIX) {
        const int yy = tid / HWD;
        const int xx = tid - yy * HWD;
        const int gy = ty0 + yy - RAD;
        const int gx = tx0 + xx - RAD;
        const bool in = ((unsigned)gy < (unsigned)IMG) & ((unsigned)gx < (unsigned)IMG);
        const float* p = xb + gy * IMG + gx;
        unsigned pk[8];
        float ss = 0.f;
        #pragma unroll
        for (int k = 0; k < 8; ++k) {
            const float v0 = in ? p[(2 * k) * PLANE] : 0.f;
            const float v1 = in ? p[(2 * k + 1) * PLANE] : 0.f;
            const unsigned q0 = bf16rne(v0);
            const unsigned q1 = bf16rne(v1);
            pk[k] = q0 | (q1 << 16);
            const float r0 = __uint_as_float(q0 << 16);
            const float r1 = __uint_as_float(q1 << 16);
            ss = fmaf(r0, r0, ss);
            ss = fmaf(r1, r1, ss);
        }
        unsigned* rp = &recd[tid * PSTRD];
        #pragma unroll
        for (int k = 0; k < 4; ++k)
            *reinterpret_cast<uint2*>(rp + 2 * k) = make_uint2(pk[2 * k], pk[2 * k + 1]);
        rp[8] = __float_as_uint(ss);
    }
    __syncthreads();

    // ---- exact fp32 center, own 8 channels; cc completed via DPP ----
    const float* cp = xb + (size_t)(half * 8) * PLANE + (ty0 + ly) * IMG + (tx0 + lx);
    float ctr[8];
    #pragma unroll
    for (int c = 0; c < 8; ++c) ctr[c] = cp[c * PLANE];
    float cch = 0.f;
    #pragma unroll
    for (int c = 0; c < 8; ++c) cch = fmaf(ctr[c], ctr[c], cch);
    const float cc = xor1_sum(cch);

    float acc[8];
    #pragma unroll
    for (int c = 0; c < 8; ++c) acc[c] = 0.f;
    float s = 0.f;

    // ---- 49 visits; both loops fully rolled (bounded live set) ----
    #pragma unroll 1
    for (int wy = 0; wy < 7; ++wy) {
        const unsigned* rp = &recd[((ly + wy) * HWD + lx) * PSTRD + 4 * half];
        #pragma unroll 1
        for (int wx = 0; wx < 7; ++wx) {
            const uint2 q0 = *reinterpret_cast<const uint2*>(rp + 0);
            const uint2 q1 = *reinterpret_cast<const uint2*>(rp + 2);
            const float nn = __uint_as_float(rp[8 - 4 * half]);  // dword 8
            float nb[8];
            nb[0] = bl(q0.x); nb[1] = bh(q0.x);
            nb[2] = bl(q0.y); nb[3] = bh(q0.y);
            nb[4] = bl(q1.x); nb[5] = bh(q1.x);
            nb[6] = bl(q1.y); nb[7] = bh(q1.y);
            float d0 = 0.f, d1 = 0.f;
            #pragma unroll
            for (int c = 0; c < 8; c += 2) {
                d0 = fmaf(nb[c + 0], ctr[c + 0], d0);
                d1 = fmaf(nb[c + 1], ctr[c + 1], d1);
            }
            const float dot = xor1_sum(d0 + d1);        // full 16-ch dot
            const float w = __expf(fmaf(2.f, dot, -(nn + cc)));
            s += w;
            #pragma unroll
            for (int c = 0; c < 8; ++c) acc[c] = fmaf(w, nb[c], acc[c]);
            rp += PSTRD;
        }
    }

    const float inv = 1.f / s;
    float* ob = out + (size_t)(b * 64 + g * MID + half * 8) * PLANE
                    + (size_t)(ty0 + ly) * IMG + (tx0 + lx);
    #pragma unroll
    for (int c = 0; c < 8; ++c)
        ob[c * PLANE] = fmaf(acc[c], inv, ctr[c]);
}

extern "C" void kernel_launch(void* const* d_in, const int* in_sizes, int n_in,
                              void* d_out, int out_size, void* d_ws, size_t ws_size,
                              hipStream_t stream) {
    const float* x = (const float*)d_in[0];
    float* out = (float*)d_out;
    dim3 grid(IMG / TW, IMG / TW, 16);   // 8 x 8 x (B=4 * HEADS=4) = 1024 blocks
    nlm_kernel<<<grid, 512, 0, stream>>>(x, out);
}